// Round 1
// baseline (387.823 us; speedup 1.0000x reference)
//
#include <hip/hip_runtime.h>
#include <stdint.h>

#define C_HID 128
#define NGRAPH 64
#define COUT 64
#define POOL_S 64     // pool chunks per graph
#define NBLK 256      // edge-chunk blocks for cnt/scat
#define BKT 256       // nodes per bucket
#define NBUK_MAX 512
#define SCAN_CH 4096  // scan elements per block (256 thr x 16)

typedef short bf16x8 __attribute__((ext_vector_type(8)));
typedef float f32x4 __attribute__((ext_vector_type(4)));
typedef float f32x2 __attribute__((ext_vector_type(2)));

__device__ __forceinline__ unsigned short f2bf(float f){
  unsigned int u = __builtin_bit_cast(unsigned int, f);
  u = u + 0x7FFFu + ((u >> 16) & 1u);   // RNE
  return (unsigned short)(u >> 16);
}
__device__ __forceinline__ float bflo(unsigned int u){
  return __builtin_bit_cast(float, u << 16);
}
__device__ __forceinline__ float bfhi(unsigned int u){
  return __builtin_bit_cast(float, u & 0xFFFF0000u);
}
__device__ __forceinline__ int clampi(int v, int lo, int hi){
  return v < lo ? lo : (v > hi ? hi : v);
}

__global__ void k_zero(float* __restrict__ out, int n){
  int i = blockIdx.x*blockDim.x + threadIdx.x;
  if (i < n) out[i] = 0.f;
}

// ---------- CSR build, pass 1: per-(block,bucket) histogram ----------
__global__ __launch_bounds__(256) void k_cnt(const int* __restrict__ dst,
                                             int* __restrict__ cntg,
                                             int E, int N, int NBUK, int chunk){
  __shared__ int cnt[NBUK_MAX];
  int blk = blockIdx.x, t = threadIdx.x;
  for (int b = t; b < NBUK; b += 256) cnt[b] = 0;
  __syncthreads();
  int e0 = blk*chunk, e1 = min(E, e0 + chunk);
  for (int e = e0 + t; e < e1; e += 256)
    atomicAdd(&cnt[clampi(dst[e], 0, N-1) >> 8], 1);
  __syncthreads();
  for (int b = t; b < NBUK; b += 256)
    cntg[b*NBLK + blk] = cnt[b];          // bucket-major layout for the scan
}

// ---------- pass 2: hierarchical exclusive scan of n counts ----------
__global__ __launch_bounds__(256) void k_scanA(const int* __restrict__ cnt,
                                               int* __restrict__ bsum, int n){
  __shared__ int red[256];
  int blk = blockIdx.x, t = threadIdx.x;
  int base = blk*SCAN_CH + t*16;
  int s = 0;
  #pragma unroll
  for (int j = 0; j < 16; ++j){ int i = base + j; s += (i < n) ? cnt[i] : 0; }
  red[t] = s; __syncthreads();
  for (int off = 128; off > 0; off >>= 1){
    if (t < off) red[t] += red[t + off];
    __syncthreads();
  }
  if (t == 0) bsum[blk] = red[0];
}

// single block; nb <= 256
__global__ __launch_bounds__(256) void k_scanB(const int* __restrict__ bsum,
                                               int* __restrict__ bbase,
                                               int* __restrict__ bases, int nb, int n){
  __shared__ int buf[256];
  int t = threadIdx.x;
  int v = (t < nb) ? bsum[t] : 0;
  buf[t] = v; __syncthreads();
  for (int off = 1; off < 256; off <<= 1){
    int add = (t >= off) ? buf[t-off] : 0;
    __syncthreads();
    buf[t] += add;
    __syncthreads();
  }
  if (t < nb) bbase[t] = buf[t] - v;       // exclusive
  if (t == nb-1) bases[n] = buf[t];        // total == E
}

__global__ __launch_bounds__(256) void k_scanC(const int* __restrict__ cnt,
                                               const int* __restrict__ bbase,
                                               int* __restrict__ bases, int n){
  __shared__ int buf[256];
  int blk = blockIdx.x, t = threadIdx.x;
  int base = blk*SCAN_CH + t*16;
  int loc[16]; int s = 0;
  #pragma unroll
  for (int j = 0; j < 16; ++j){ int i = base + j; loc[j] = (i < n) ? cnt[i] : 0; s += loc[j]; }
  buf[t] = s; __syncthreads();
  for (int off = 1; off < 256; off <<= 1){
    int add = (t >= off) ? buf[t-off] : 0;
    __syncthreads();
    buf[t] += add;
    __syncthreads();
  }
  int run = bbase[blk] + buf[t] - s;       // exclusive prefix for this thread
  #pragma unroll
  for (int j = 0; j < 16; ++j){
    int i = base + j;
    if (i < n) bases[i] = run;
    run += loc[j];
  }
}

// ---------- pass 3: scatter packed records into per-(block,bucket) segments ----------
__global__ __launch_bounds__(256) void k_scat(const int* __restrict__ src,
                                              const int* __restrict__ dst,
                                              const int* __restrict__ bases,
                                              unsigned int* __restrict__ rec,
                                              int E, int N, int NBUK, int chunk){
  __shared__ int cur[NBUK_MAX];
  int blk = blockIdx.x, t = threadIdx.x;
  for (int b = t; b < NBUK; b += 256) cur[b] = bases[b*NBLK + blk];
  __syncthreads();
  int e0 = blk*chunk, e1 = min(E, e0 + chunk);
  for (int e = e0 + t; e < e1; e += 256){
    int d = clampi(dst[e], 0, N-1);
    int s = clampi(src[e], 0, N-1);
    int p = atomicAdd(&cur[d >> 8], 1);    // LDS atomic
    rec[p] = (unsigned int)s | ((unsigned int)(d & 255) << 24);
  }
}

// ---------- pass 4: per-bucket local CSR (offs, dinv, meta) ----------
__global__ __launch_bounds__(256) void k_csr(const unsigned int* __restrict__ rec,
                                             const int* __restrict__ bases,
                                             int* __restrict__ offs, float* __restrict__ dinv,
                                             int* __restrict__ meta, int E, int N, int NBUK){
  __shared__ int cnt[BKT], loff[BKT], cur[BKT];
  int b = blockIdx.x, t = threadIdx.x;
  cnt[t] = 0;
  __syncthreads();
  int r0 = bases[b*NBLK];
  int r1 = (b+1 < NBUK) ? bases[(b+1)*NBLK] : E;
  for (int i = r0 + t; i < r1; i += 256)
    atomicAdd(&cnt[rec[i] >> 24], 1);
  __syncthreads();
  loff[t] = cnt[t];
  __syncthreads();
  for (int off = 1; off < BKT; off <<= 1){
    int add = (t >= off) ? loff[t - off] : 0;
    __syncthreads();
    loff[t] += add;
    __syncthreads();
  }
  int excl = loff[t] - cnt[t];
  cur[t] = r0 + excl;
  int node = b*BKT + t;
  if (node < N){
    offs[node] = r0 + excl;
    dinv[node] = rsqrtf((float)(cnt[t] + 1));   // +1 = self loop
  }
  if (b == NBUK-1 && t == 0) offs[N] = E;
  __syncthreads();
  for (int i = r0 + t; i < r1; i += 256){
    unsigned int r = rec[i];
    int p = atomicAdd(&cur[r >> 24], 1);
    meta[p] = (int)(r & 0x00FFFFFFu);
  }
}

// ---------- y0 = 64*dinv*x0, fp32 -> fp8 e4m3; zero row N of BOTH fp8 buffers ----------
// S=64 (exact pow2) keeps y values in e4m3's normal range (~0.1..80).
__global__ void k_xcast(const float2* __restrict__ x, const float* __restrict__ dinv,
                        unsigned short* __restrict__ y, unsigned short* __restrict__ y2, int N){
  int i = blockIdx.x*256 + threadIdx.x;
  int tot = N*64;
  if (i < tot){
    float2 v = x[i];
    float dn = dinv[i >> 6] * 64.f;
    int p = __builtin_amdgcn_cvt_pk_fp8_f32(v.x*dn, v.y*dn, 0, false);
    y[i] = (unsigned short)(p & 0xFFFF);
  } else if (i < tot + 64){
    y[i] = 0;                       // zero row at index N (gather sink)
    y2[i] = 0;
  }
}

// ---------- W fp32 [128][128] -> Wt bf16 [n][k] (3 weights) ----------
__global__ void k_prep(const float* __restrict__ W1, const float* __restrict__ W2,
                       const float* __restrict__ W3, unsigned short* __restrict__ Wt){
  int idx = blockIdx.x*256 + threadIdx.x;     // grid = 192 blocks
  int w = idx >> 14;                           // 16384 per weight
  int r = idx & 16383;
  int n = r & 127, k = r >> 7;
  const float* W = (w == 0) ? W1 : (w == 1) ? W2 : W3;
  Wt[(size_t)w*16384 + (size_t)n*128 + k] = f2bf(W[k*128 + n]);
}

// ---------- SpMM v2: agg[i] = (dinv[i]/64) * ( y[i] + sum_e y[src_e] ), y fp8 ----------
// Latency-bound fix: one wave per node, but
//   (1) ALL meta srcs loaded in ONE per-lane instr (mv = meta[e0+lane], deg<=63 ~always),
//       broadcast per-slot via shfl -> kills the per-batch s_load serialization;
//   (2) 8B/lane dwordx2 gathers, 4 edges/instr (512B/instr), ALL <=8 gather instrs
//       issued back-to-back before any consume (sched_barrier pins the split)
//       -> ~2.5KB in flight per wave, ONE latency round instead of three;
//   (3) butterfly reduce across the 4 edge-groups (xor 16,32), pack bf16 on g==0
//       lanes, single 256B dwordx4 row store.
__global__ __launch_bounds__(256) void k_spmm(const unsigned short* __restrict__ y,
                       const int* __restrict__ offs,
                       const float* __restrict__ dinv,
                       const int* __restrict__ meta,
                       unsigned int* __restrict__ agg, int N){
  int wv   = __builtin_amdgcn_readfirstlane(threadIdx.x >> 6);
  int lane = threadIdx.x & 63;
  int node = blockIdx.x*4 + wv;
  if (node >= N) return;
  int g = lane >> 4;                 // edge-slot group 0..3
  int c = lane & 15;                 // channel block: bytes c*8 .. c*8+7 of the row

  int e0 = offs[node], e1 = offs[node+1];   // node is SGPR -> s_load
  int cnt = e1 - e0;
  // preload up to 64 edge srcs in one per-lane load; N-fill beyond cnt
  int mv = (lane < cnt) ? meta[e0 + lane] : N;

  const uint2* yrow = (const uint2*)y;      // row = 16 x 8B

  f32x2 acc[4];
  #pragma unroll
  for (int k = 0; k < 4; ++k) acc[k] = (f32x2){0.f, 0.f};

  int nslot = cnt + 1;                      // slot 0 = self loop
  int ninstr = (nslot + 3) >> 2;
  if (ninstr > 8) ninstr = 8;

  uint2 u[8];
  #pragma unroll
  for (int k = 0; k < 8; ++k){
    if (k < ninstr){                        // wave-uniform guard
      int slot = k*4 + g;                   // 0..31
      int idx  = slot - 1;                  // edge index, -1 = self
      int idxc = idx < 0 ? 0 : idx;         // <= 30 < 64, mv covers (N-filled past cnt)
      int sj = __shfl(mv, idxc, 64);
      if (slot == 0) sj = node;             // self loop
      u[k] = yrow[(size_t)sj*16 + c];
    }
  }
  __builtin_amdgcn_sched_barrier(0);        // keep all gathers issued before consume
  #pragma unroll
  for (int k = 0; k < 8; ++k){
    if (k < ninstr){
      f32x2 f;
      f = __builtin_amdgcn_cvt_pk_f32_fp8((int)u[k].x, false); acc[0] += f;
      f = __builtin_amdgcn_cvt_pk_f32_fp8((int)u[k].x, true);  acc[1] += f;
      f = __builtin_amdgcn_cvt_pk_f32_fp8((int)u[k].y, false); acc[2] += f;
      f = __builtin_amdgcn_cvt_pk_f32_fp8((int)u[k].y, true);  acc[3] += f;
    }
  }
  // rare tail: slots 32..nslot-1 (P[deg>31] ~ 2e-4 for Poisson(16); correctness only)
  for (int base = 32; base < nslot; base += 4){
    int idx = base + g - 1;
    int sj = (idx < cnt) ? meta[e0 + idx] : N;
    uint2 t = yrow[(size_t)sj*16 + c];
    f32x2 f;
    f = __builtin_amdgcn_cvt_pk_f32_fp8((int)t.x, false); acc[0] += f;
    f = __builtin_amdgcn_cvt_pk_f32_fp8((int)t.x, true);  acc[1] += f;
    f = __builtin_amdgcn_cvt_pk_f32_fp8((int)t.y, false); acc[2] += f;
    f = __builtin_amdgcn_cvt_pk_f32_fp8((int)t.y, true);  acc[3] += f;
  }
  // butterfly across the 4 edge groups (lanes differ in bits 4,5)
  #pragma unroll
  for (int k = 0; k < 4; ++k){
    acc[k].x += __shfl_xor(acc[k].x, 16, 64);
    acc[k].y += __shfl_xor(acc[k].y, 16, 64);
    acc[k].x += __shfl_xor(acc[k].x, 32, 64);
    acc[k].y += __shfl_xor(acc[k].y, 32, 64);
  }
  float dn = dinv[node] * 0.015625f;   // /64
  if (g == 0){
    uint4 w;
    w.x = (unsigned int)f2bf(acc[0].x*dn) | ((unsigned int)f2bf(acc[0].y*dn) << 16);
    w.y = (unsigned int)f2bf(acc[1].x*dn) | ((unsigned int)f2bf(acc[1].y*dn) << 16);
    w.z = (unsigned int)f2bf(acc[2].x*dn) | ((unsigned int)f2bf(acc[2].y*dn) << 16);
    w.w = (unsigned int)f2bf(acc[3].x*dn) | ((unsigned int)f2bf(acc[3].y*dn) << 16);
    *(uint4*)(agg + (size_t)node*64 + c*4) = w;   // 16 lanes x 16B = 256B row
  }
}

// ---------- GEMM: h = relu(A[Mx128] @ W + b); FP8OUT: y' = fp8(64*dinv*h), else bf16 h ----
#define GEMM_BLOCKS 512
template<bool FP8OUT>
__global__ __launch_bounds__(256) void k_gemm(const unsigned short* __restrict__ A,
                                              const unsigned short* __restrict__ Wt,
                                              const float* __restrict__ bias,
                                              const float* __restrict__ scale,
                                              void* __restrict__ outv, int M){
  __shared__ unsigned short wt[128*136];
  {
    const uint4* wsrc = (const uint4*)Wt;     // 4096 uint4 (8 shorts each)
    for (int i = threadIdx.x; i < 4096; i += 256){
      uint4 v = wsrc[i];
      int n = i >> 4, kblk = i & 15;          // row = 16 uint4
      *(uint4*)&wt[n*136 + kblk*8] = v;
    }
  }
  __syncthreads();

  int wv = threadIdx.x >> 6, lane = threadIdx.x & 63;
  int q = lane >> 4, ln = lane & 15;
  int tiles = (M + 63) >> 6;

  for (int tile = blockIdx.x; tile < tiles; tile += GEMM_BLOCKS){
    int m0 = tile*64 + wv*16;
    int arow = m0 + ln;
    bool arow_ok = (arow < M);
    int arow_s = arow_ok ? arow : 0;

    f32x4 zero = {0.f, 0.f, 0.f, 0.f};
    f32x4 acc[8];
    #pragma unroll
    for (int t = 0; t < 8; ++t) acc[t] = zero;

    #pragma unroll
    for (int kk = 0; kk < 4; ++kk){
      bf16x8 a;
      if (arow_ok){
        __builtin_memcpy(&a, A + (size_t)arow_s*128 + kk*32 + q*8, 16);
      } else {
        a = (bf16x8){0,0,0,0,0,0,0,0};
      }
      #pragma unroll
      for (int t = 0; t < 8; ++t){
        bf16x8 b;
        __builtin_memcpy(&b, &wt[(t*16 + ln)*136 + kk*32 + q*8], 16);
        acc[t] = __builtin_amdgcn_mfma_f32_16x16x32_bf16(a, b, acc[t], 0, 0, 0);
      }
    }
    float sc[4];
    #pragma unroll
    for (int r = 0; r < 4; ++r){
      int row = m0 + q*4 + r;
      sc[r] = (FP8OUT && row < M) ? scale[row] * 64.f : 1.0f;
    }
    #pragma unroll
    for (int t = 0; t < 8; ++t){
      float bv = bias[t*16 + ln];
      #pragma unroll
      for (int r = 0; r < 4; ++r){
        int row = m0 + q*4 + r;
        if (row < M){
          float v = acc[t][r] + bv;
          v = v > 0.f ? v : 0.f;
          if (FP8OUT){
            v *= sc[r];
            int p = __builtin_amdgcn_cvt_pk_fp8_f32(v, v, 0, false);
            ((unsigned char*)outv)[(size_t)row*128 + t*16 + ln] = (unsigned char)(p & 0xFF);
          } else {
            ((unsigned short*)outv)[(size_t)row*128 + t*16 + ln] = f2bf(v);
          }
        }
      }
    }
  }
}

// ---------- pooling ----------
__device__ __forceinline__ int lower_bound_i(const int* arr, int n, int val){
  int lo = 0, hi = n;
  while (lo < hi){ int mid = (lo + hi) >> 1; if (arr[mid] < val) lo = mid + 1; else hi = mid; }
  return lo;
}

__global__ void k_pool(const unsigned int* __restrict__ x, const int* __restrict__ batch,
                       float* __restrict__ partial, int N){
  int g = blockIdx.x / POOL_S, s = blockIdx.x % POOL_S;
  int h = threadIdx.x >> 6;
  int lane = threadIdx.x & 63;
  int rs = clampi(lower_bound_i(batch, N, g), 0, N);
  int re = clampi(lower_bound_i(batch, N, g + 1), rs, N);
  int len = re - rs;
  int a = rs + (int)(((long long)len * s) / POOL_S);
  int b = rs + (int)(((long long)len * (s + 1)) / POOL_S);
  float ax = 0.f, ay = 0.f;
  for (int i = a + h; i < b; i += 2){
    unsigned int u = x[(size_t)i*64 + lane];
    ax += bflo(u);
    ay += bfhi(u);
  }
  float* p = partial + ((size_t)(g*POOL_S + s)*2 + h)*C_HID;
  p[2*lane]   = ax;
  p[2*lane+1] = ay;
}

__global__ void k_final(const float* __restrict__ partial, const int* __restrict__ batch,
                        const float* __restrict__ Wl, const float* __restrict__ bl,
                        float* __restrict__ out, int N){
  __shared__ float sums[C_HID];
  int g = blockIdx.x;
  int t = threadIdx.x;
  float acc = 0.f;
  const float* p = partial + (size_t)g*POOL_S*2*C_HID;
  for (int j = 0; j < POOL_S*2; ++j)
    acc += p[j*C_HID + t];
  sums[t] = acc;
  __syncthreads();
  if (t < COUT){
    int rs = clampi(lower_bound_i(batch, N, g), 0, N);
    int re = clampi(lower_bound_i(batch, N, g + 1), rs, N);
    float inv = 1.0f / fmaxf((float)(re - rs), 1.0f);
    float o = 0.f;
    for (int k = 0; k < 128; ++k)
      o += sums[k] * Wl[k*COUT + t];
    out[g*COUT + t] = o * inv + bl[t];
  }
}

extern "C" void kernel_launch(void* const* d_in, const int* in_sizes, int n_in,
                              void* d_out, int out_size, void* d_ws, size_t ws_size,
                              hipStream_t stream){
  const float* x0 = (const float*)d_in[0];
  const int* ei   = (const int*)d_in[1];
  const int* batch= (const int*)d_in[2];
  const float* W1 = (const float*)d_in[3];
  const float* b1 = (const float*)d_in[4];
  const float* W2 = (const float*)d_in[5];
  const float* b2 = (const float*)d_in[6];
  const float* W3 = (const float*)d_in[7];
  const float* b3 = (const float*)d_in[8];
  const float* Wl = (const float*)d_in[9];
  const float* bl = (const float*)d_in[10];
  float* out = (float*)d_out;

  int E = in_sizes[1] / 2;
  int N = in_sizes[2];
  const int* src = ei;
  const int* dst = ei + E;
  int NBUK = (N + BKT - 1) / BKT;
  int chunk = (E + NBLK - 1) / NBLK;
  int ncnt = NBUK * NBLK;
  int nsb  = (ncnt + SCAN_CH - 1) / SCAN_CH;   // scan blocks

  size_t off_acc = 0;
  auto carve = [&](size_t bytes)->size_t{
    size_t r = off_acc; off_acc += (bytes + 255) & ~(size_t)255; return r;
  };
  size_t o_cnt   = carve((size_t)ncnt*4);
  size_t o_bases = carve((size_t)(ncnt+1)*4);
  size_t o_bsum  = carve(256*4);
  size_t o_bbase = carve(256*4);
  size_t o_offs  = carve((size_t)(N+1)*4);
  size_t o_dinv  = carve((size_t)N*4);
  size_t o_meta  = carve((size_t)E*4);                      // compact CSR src list
  size_t o_rec   = carve((size_t)E*4);                      // bucket-sorted records
  size_t o_yA    = carve((size_t)(N+1)*C_HID);              // fp8 ping (+ zero row N)
  size_t o_yB    = carve((size_t)(N+1)*C_HID);              // fp8 pong (+ zero row N)
  size_t o_aggb  = carve((size_t)N*C_HID*2);                // bf16 agg
  size_t o_wt    = carve((size_t)3*128*128*2);              // bf16 Wt x3
  size_t need = off_acc;

  // hbuf (bf16 h3, 25.6MB) aliases meta+rec+yA (all dead after spmm3)
  size_t hbuf_avail = o_aggb - o_meta;
  bool alias_ok = hbuf_avail >= (size_t)N*C_HID*2;
  // part (4MB) aliases yB (dead after spmm3); yB region is 12.8MB
  alias_ok = alias_ok &&
             ((size_t)(N+1)*C_HID >= (size_t)NGRAPH*POOL_S*2*C_HID*4);

  if (ws_size < need || NBUK > NBUK_MAX || nsb > 256 || !alias_ok){
    k_zero<<<(out_size+255)/256, 256, 0, stream>>>(out, out_size);
    return;
  }

  char* base = (char*)d_ws;
  int* cntg  = (int*)(base + o_cnt);
  int* bases = (int*)(base + o_bases);
  int* bsum  = (int*)(base + o_bsum);
  int* bbase = (int*)(base + o_bbase);
  int* offs  = (int*)(base + o_offs);
  float* dinv= (float*)(base + o_dinv);
  int* meta  = (int*)(base + o_meta);
  unsigned int* rec   = (unsigned int*)(base + o_rec);
  unsigned short* yA  = (unsigned short*)(base + o_yA);     // fp8 pairs as ushort
  unsigned short* yB  = (unsigned short*)(base + o_yB);
  unsigned int* aggb  = (unsigned int*)(base + o_aggb);
  unsigned short* wt  = (unsigned short*)(base + o_wt);
  unsigned short* hbuf= (unsigned short*)(base + o_meta);   // alias: meta+rec+yA region
  float* part         = (float*)(base + o_yB);              // alias: yB region

  k_cnt  <<<NBLK, 256, 0, stream>>>(dst, cntg, E, N, NBUK, chunk);
  k_scanA<<<nsb, 256, 0, stream>>>(cntg, bsum, ncnt);
  k_scanB<<<1, 256, 0, stream>>>(bsum, bbase, bases, nsb, ncnt);
  k_scanC<<<nsb, 256, 0, stream>>>(cntg, bbase, bases, ncnt);
  k_scat <<<NBLK, 256, 0, stream>>>(src, dst, bases, rec, E, N, NBUK, chunk);
  k_csr  <<<NBUK, BKT, 0, stream>>>(rec, bases, offs, dinv, meta, E, N, NBUK);

  k_xcast<<<(N*64 + 64 + 255)/256, 256, 0, stream>>>((const float2*)x0, dinv, yA, yB, N);
  k_prep <<<192, 256, 0, stream>>>(W1, W2, W3, wt);

  int spmm_grid = (N + 3) / 4;     // 4 waves/block, one wave per node

  k_spmm<<<spmm_grid, 256, 0, stream>>>(yA, offs, dinv, meta, aggb, N);
  k_gemm<true ><<<GEMM_BLOCKS, 256, 0, stream>>>((const unsigned short*)aggb, wt,           b1, dinv, (void*)yB, N);
  k_spmm<<<spmm_grid, 256, 0, stream>>>(yB, offs, dinv, meta, aggb, N);
  k_gemm<true ><<<GEMM_BLOCKS, 256, 0, stream>>>((const unsigned short*)aggb, wt + 16384,   b2, dinv, (void*)yA, N);
  k_spmm<<<spmm_grid, 256, 0, stream>>>(yA, offs, dinv, meta, aggb, N);
  k_gemm<false><<<GEMM_BLOCKS, 256, 0, stream>>>((const unsigned short*)aggb, wt + 2*16384, b3, dinv, (void*)hbuf, N);

  k_pool <<<NGRAPH*POOL_S, 128, 0, stream>>>((const unsigned int*)hbuf, batch, part, N);
  k_final<<<NGRAPH, 128, 0, stream>>>(part, batch, Wl, bl, out, N);
}

// Round 3
// 379.140 us; speedup vs baseline: 1.0229x; 1.0229x over previous
//
#include <hip/hip_runtime.h>
#include <stdint.h>

#define C_HID 128
#define NGRAPH 64
#define COUT 64
#define POOL_S 64     // pool chunks per graph
#define NBLK 256      // edge-chunk blocks for cnt/scat
#define BKT 256       // nodes per bucket
#define NBUK_MAX 512
#define SCAN_CH 4096  // scan elements per block (256 thr x 16)

typedef short bf16x8 __attribute__((ext_vector_type(8)));
typedef float f32x4 __attribute__((ext_vector_type(4)));
typedef float f32x2 __attribute__((ext_vector_type(2)));

__device__ __forceinline__ unsigned short f2bf(float f){
  unsigned int u = __builtin_bit_cast(unsigned int, f);
  u = u + 0x7FFFu + ((u >> 16) & 1u);   // RNE
  return (unsigned short)(u >> 16);
}
__device__ __forceinline__ float bflo(unsigned int u){
  return __builtin_bit_cast(float, u << 16);
}
__device__ __forceinline__ float bfhi(unsigned int u){
  return __builtin_bit_cast(float, u & 0xFFFF0000u);
}
__device__ __forceinline__ int clampi(int v, int lo, int hi){
  return v < lo ? lo : (v > hi ? hi : v);
}

__global__ void k_zero(float* __restrict__ out, int n){
  int i = blockIdx.x*blockDim.x + threadIdx.x;
  if (i < n) out[i] = 0.f;
}

// ---------- CSR build, pass 1: per-(block,bucket) histogram ----------
__global__ __launch_bounds__(256) void k_cnt(const int* __restrict__ dst,
                                             int* __restrict__ cntg,
                                             int E, int N, int NBUK, int chunk){
  __shared__ int cnt[NBUK_MAX];
  int blk = blockIdx.x, t = threadIdx.x;
  for (int b = t; b < NBUK; b += 256) cnt[b] = 0;
  __syncthreads();
  int e0 = blk*chunk, e1 = min(E, e0 + chunk);
  for (int e = e0 + t; e < e1; e += 256)
    atomicAdd(&cnt[clampi(dst[e], 0, N-1) >> 8], 1);
  __syncthreads();
  for (int b = t; b < NBUK; b += 256)
    cntg[b*NBLK + blk] = cnt[b];          // bucket-major layout for the scan
}

// ---------- pass 2: hierarchical exclusive scan of n counts ----------
__global__ __launch_bounds__(256) void k_scanA(const int* __restrict__ cnt,
                                               int* __restrict__ bsum, int n){
  __shared__ int red[256];
  int blk = blockIdx.x, t = threadIdx.x;
  int base = blk*SCAN_CH + t*16;
  int s = 0;
  #pragma unroll
  for (int j = 0; j < 16; ++j){ int i = base + j; s += (i < n) ? cnt[i] : 0; }
  red[t] = s; __syncthreads();
  for (int off = 128; off > 0; off >>= 1){
    if (t < off) red[t] += red[t + off];
    __syncthreads();
  }
  if (t == 0) bsum[blk] = red[0];
}

// single block; nb <= 256
__global__ __launch_bounds__(256) void k_scanB(const int* __restrict__ bsum,
                                               int* __restrict__ bbase,
                                               int* __restrict__ bases, int nb, int n){
  __shared__ int buf[256];
  int t = threadIdx.x;
  int v = (t < nb) ? bsum[t] : 0;
  buf[t] = v; __syncthreads();
  for (int off = 1; off < 256; off <<= 1){
    int add = (t >= off) ? buf[t-off] : 0;
    __syncthreads();
    buf[t] += add;
    __syncthreads();
  }
  if (t < nb) bbase[t] = buf[t] - v;       // exclusive
  if (t == nb-1) bases[n] = buf[t];        // total == E
}

__global__ __launch_bounds__(256) void k_scanC(const int* __restrict__ cnt,
                                               const int* __restrict__ bbase,
                                               int* __restrict__ bases, int n){
  __shared__ int buf[256];
  int blk = blockIdx.x, t = threadIdx.x;
  int base = blk*SCAN_CH + t*16;
  int loc[16]; int s = 0;
  #pragma unroll
  for (int j = 0; j < 16; ++j){ int i = base + j; loc[j] = (i < n) ? cnt[i] : 0; s += loc[j]; }
  buf[t] = s; __syncthreads();
  for (int off = 1; off < 256; off <<= 1){
    int add = (t >= off) ? buf[t-off] : 0;
    __syncthreads();
    buf[t] += add;
    __syncthreads();
  }
  int run = bbase[blk] + buf[t] - s;       // exclusive prefix for this thread
  #pragma unroll
  for (int j = 0; j < 16; ++j){
    int i = base + j;
    if (i < n) bases[i] = run;
    run += loc[j];
  }
}

// ---------- pass 3: scatter packed records into per-(block,bucket) segments ----------
__global__ __launch_bounds__(256) void k_scat(const int* __restrict__ src,
                                              const int* __restrict__ dst,
                                              const int* __restrict__ bases,
                                              unsigned int* __restrict__ rec,
                                              int E, int N, int NBUK, int chunk){
  __shared__ int cur[NBUK_MAX];
  int blk = blockIdx.x, t = threadIdx.x;
  for (int b = t; b < NBUK; b += 256) cur[b] = bases[b*NBLK + blk];
  __syncthreads();
  int e0 = blk*chunk, e1 = min(E, e0 + chunk);
  for (int e = e0 + t; e < e1; e += 256){
    int d = clampi(dst[e], 0, N-1);
    int s = clampi(src[e], 0, N-1);
    int p = atomicAdd(&cur[d >> 8], 1);    // LDS atomic
    rec[p] = (unsigned int)s | ((unsigned int)(d & 255) << 24);
  }
}

// ---------- pass 4: per-bucket local CSR (offs, dinv, meta) ----------
__global__ __launch_bounds__(256) void k_csr(const unsigned int* __restrict__ rec,
                                             const int* __restrict__ bases,
                                             int* __restrict__ offs, float* __restrict__ dinv,
                                             int* __restrict__ meta, int E, int N, int NBUK){
  __shared__ int cnt[BKT], loff[BKT], cur[BKT];
  int b = blockIdx.x, t = threadIdx.x;
  cnt[t] = 0;
  __syncthreads();
  int r0 = bases[b*NBLK];
  int r1 = (b+1 < NBUK) ? bases[(b+1)*NBLK] : E;
  for (int i = r0 + t; i < r1; i += 256)
    atomicAdd(&cnt[rec[i] >> 24], 1);
  __syncthreads();
  loff[t] = cnt[t];
  __syncthreads();
  for (int off = 1; off < BKT; off <<= 1){
    int add = (t >= off) ? loff[t - off] : 0;
    __syncthreads();
    loff[t] += add;
    __syncthreads();
  }
  int excl = loff[t] - cnt[t];
  cur[t] = r0 + excl;
  int node = b*BKT + t;
  if (node < N){
    offs[node] = r0 + excl;
    dinv[node] = rsqrtf((float)(cnt[t] + 1));   // +1 = self loop
  }
  if (b == NBUK-1 && t == 0) offs[N] = E;
  __syncthreads();
  for (int i = r0 + t; i < r1; i += 256){
    unsigned int r = rec[i];
    int p = atomicAdd(&cur[r >> 24], 1);
    meta[p] = (int)(r & 0x00FFFFFFu);
  }
}

// ---------- y0 = 64*dinv*x0, fp32 -> fp8 e4m3; zero row N of BOTH fp8 buffers ----------
// S=64 (exact pow2) keeps y values in e4m3's normal range (~0.1..80).
__global__ void k_xcast(const float2* __restrict__ x, const float* __restrict__ dinv,
                        unsigned short* __restrict__ y, unsigned short* __restrict__ y2, int N){
  int i = blockIdx.x*256 + threadIdx.x;
  int tot = N*64;
  if (i < tot){
    float2 v = x[i];
    float dn = dinv[i >> 6] * 64.f;
    int p = __builtin_amdgcn_cvt_pk_fp8_f32(v.x*dn, v.y*dn, 0, false);
    y[i] = (unsigned short)(p & 0xFFFF);
  } else if (i < tot + 64){
    y[i] = 0;                       // zero row at index N (gather sink)
    y2[i] = 0;
  }
}

// ---------- W fp32 [128][128] -> Wt bf16 [n][k] (3 weights) ----------
__global__ void k_prep(const float* __restrict__ W1, const float* __restrict__ W2,
                       const float* __restrict__ W3, unsigned short* __restrict__ Wt){
  int idx = blockIdx.x*256 + threadIdx.x;     // grid = 192 blocks
  int w = idx >> 14;                           // 16384 per weight
  int r = idx & 16383;
  int n = r & 127, k = r >> 7;
  const float* W = (w == 0) ? W1 : (w == 1) ? W2 : W3;
  Wt[(size_t)w*16384 + (size_t)n*128 + k] = f2bf(W[k*128 + n]);
}

// ---------- SpMM v3: agg[i] = (dinv[i]/64) * ( y[i] + sum_e y[src_e] ), y fp8 ----------
// v1's cheap addressing (uniform meta -> s_load, SGPR row base + lane*2B gathers,
// zero shuffles) but ONE latency round: all <=32 meta s_loads issued upfront
// (independent -> single lgkm round), then ALL row gathers issued back-to-back
// (wave-uniform guards at granularity 8; sched_barrier pins issue-before-consume).
// v2 post-mortem: shfl-broadcast + per-lane addressing + butterfly doubled VALU
// (25%->44% busy) and did NOT cut rounds (meta gather itself is a VMEM round).
__global__ __launch_bounds__(256) void k_spmm(const unsigned short* __restrict__ y,
                       const int* __restrict__ offs,
                       const float* __restrict__ dinv,
                       const int* __restrict__ meta,
                       unsigned int* __restrict__ agg, int N){
  int wv   = __builtin_amdgcn_readfirstlane(threadIdx.x >> 6);
  int lane = threadIdx.x & 63;
  int node = blockIdx.x*4 + wv;
  if (node >= N) return;
  int e0 = offs[node], e1 = offs[node+1];   // node uniform -> s_load
  int cnt = e1 - e0;
  const int* mrow = meta + e0;

  // all meta upfront: 32 independent uniform loads -> one lgkm latency round.
  // junk reads past cnt stay inside workspace (rec region follows meta); value
  // is replaced by N (zero row) before use.
  int sidx[32];
  #pragma unroll
  for (int j = 0; j < 32; ++j){
    int sj = mrow[j];
    sidx[j] = (j < cnt) ? sj : N;
  }

  // issue ALL gathers back-to-back: self + up to 32 edge rows, 128B coalesced each
  unsigned short uself = y[(size_t)node*64 + lane];
  unsigned short u[32];
  #pragma unroll
  for (int b = 0; b < 4; ++b){
    if (b*8 < cnt){                        // wave-uniform guard
      #pragma unroll
      for (int j = b*8; j < b*8 + 8; ++j)
        u[j] = y[(size_t)sidx[j]*64 + lane];   // SGPR base + lane*2B
    }
  }
  __builtin_amdgcn_sched_barrier(0);       // keep all issues ahead of first consume

  float ax, ay;
  { f32x2 f = __builtin_amdgcn_cvt_pk_f32_fp8((int)uself, false);
    ax = f.x; ay = f.y; }                  // self loop
  #pragma unroll
  for (int b = 0; b < 4; ++b){
    if (b*8 < cnt){
      #pragma unroll
      for (int j = b*8; j < b*8 + 8; ++j){
        f32x2 f = __builtin_amdgcn_cvt_pk_f32_fp8((int)u[j], false);
        ax += f.x;
        ay += f.y;
      }
    }
  }

  // rare tail (deg > 32; P ~ 1e-4 for Poisson(16)): v1-style batched loop
  for (int e = 32; e < cnt; e += 8){
    int s[8]; unsigned short t[8];
    #pragma unroll
    for (int j = 0; j < 8; ++j){
      int ij = e + j;
      int sj = mrow[ij];
      s[j] = (ij < cnt) ? sj : N;
    }
    #pragma unroll
    for (int j = 0; j < 8; ++j)
      t[j] = y[(size_t)s[j]*64 + lane];
    #pragma unroll
    for (int j = 0; j < 8; ++j){
      f32x2 f = __builtin_amdgcn_cvt_pk_f32_fp8((int)t[j], false);
      ax += f.x;
      ay += f.y;
    }
  }

  float dn = dinv[node] * 0.015625f;   // /64
  ax *= dn; ay *= dn;
  agg[(size_t)node*64 + lane] = (unsigned int)f2bf(ax) | ((unsigned int)f2bf(ay) << 16);
}

// ---------- GEMM: h = relu(A[Mx128] @ W + b); FP8OUT: y' = fp8(64*dinv*h), else bf16 h ----
#define GEMM_BLOCKS 512
template<bool FP8OUT>
__global__ __launch_bounds__(256) void k_gemm(const unsigned short* __restrict__ A,
                                              const unsigned short* __restrict__ Wt,
                                              const float* __restrict__ bias,
                                              const float* __restrict__ scale,
                                              void* __restrict__ outv, int M){
  __shared__ unsigned short wt[128*136];
  {
    const uint4* wsrc = (const uint4*)Wt;     // 4096 uint4 (8 shorts each)
    for (int i = threadIdx.x; i < 4096; i += 256){
      uint4 v = wsrc[i];
      int n = i >> 4, kblk = i & 15;          // row = 16 uint4
      *(uint4*)&wt[n*136 + kblk*8] = v;
    }
  }
  __syncthreads();

  int wv = threadIdx.x >> 6, lane = threadIdx.x & 63;
  int q = lane >> 4, ln = lane & 15;
  int tiles = (M + 63) >> 6;

  for (int tile = blockIdx.x; tile < tiles; tile += GEMM_BLOCKS){
    int m0 = tile*64 + wv*16;
    int arow = m0 + ln;
    bool arow_ok = (arow < M);
    int arow_s = arow_ok ? arow : 0;

    f32x4 zero = {0.f, 0.f, 0.f, 0.f};
    f32x4 acc[8];
    #pragma unroll
    for (int t = 0; t < 8; ++t) acc[t] = zero;

    #pragma unroll
    for (int kk = 0; kk < 4; ++kk){
      bf16x8 a;
      if (arow_ok){
        __builtin_memcpy(&a, A + (size_t)arow_s*128 + kk*32 + q*8, 16);
      } else {
        a = (bf16x8){0,0,0,0,0,0,0,0};
      }
      #pragma unroll
      for (int t = 0; t < 8; ++t){
        bf16x8 b;
        __builtin_memcpy(&b, &wt[(t*16 + ln)*136 + kk*32 + q*8], 16);
        acc[t] = __builtin_amdgcn_mfma_f32_16x16x32_bf16(a, b, acc[t], 0, 0, 0);
      }
    }
    float sc[4];
    #pragma unroll
    for (int r = 0; r < 4; ++r){
      int row = m0 + q*4 + r;
      sc[r] = (FP8OUT && row < M) ? scale[row] * 64.f : 1.0f;
    }
    #pragma unroll
    for (int t = 0; t < 8; ++t){
      float bv = bias[t*16 + ln];
      #pragma unroll
      for (int r = 0; r < 4; ++r){
        int row = m0 + q*4 + r;
        if (row < M){
          float v = acc[t][r] + bv;
          v = v > 0.f ? v : 0.f;
          if (FP8OUT){
            v *= sc[r];
            int p = __builtin_amdgcn_cvt_pk_fp8_f32(v, v, 0, false);
            ((unsigned char*)outv)[(size_t)row*128 + t*16 + ln] = (unsigned char)(p & 0xFF);
          } else {
            ((unsigned short*)outv)[(size_t)row*128 + t*16 + ln] = f2bf(v);
          }
        }
      }
    }
  }
}

// ---------- pooling ----------
__device__ __forceinline__ int lower_bound_i(const int* arr, int n, int val){
  int lo = 0, hi = n;
  while (lo < hi){ int mid = (lo + hi) >> 1; if (arr[mid] < val) lo = mid + 1; else hi = mid; }
  return lo;
}

__global__ void k_pool(const unsigned int* __restrict__ x, const int* __restrict__ batch,
                       float* __restrict__ partial, int N){
  int g = blockIdx.x / POOL_S, s = blockIdx.x % POOL_S;
  int h = threadIdx.x >> 6;
  int lane = threadIdx.x & 63;
  int rs = clampi(lower_bound_i(batch, N, g), 0, N);
  int re = clampi(lower_bound_i(batch, N, g + 1), rs, N);
  int len = re - rs;
  int a = rs + (int)(((long long)len * s) / POOL_S);
  int b = rs + (int)(((long long)len * (s + 1)) / POOL_S);
  float ax = 0.f, ay = 0.f;
  for (int i = a + h; i < b; i += 2){
    unsigned int u = x[(size_t)i*64 + lane];
    ax += bflo(u);
    ay += bfhi(u);
  }
  float* p = partial + ((size_t)(g*POOL_S + s)*2 + h)*C_HID;
  p[2*lane]   = ax;
  p[2*lane+1] = ay;
}

__global__ void k_final(const float* __restrict__ partial, const int* __restrict__ batch,
                        const float* __restrict__ Wl, const float* __restrict__ bl,
                        float* __restrict__ out, int N){
  __shared__ float sums[C_HID];
  int g = blockIdx.x;
  int t = threadIdx.x;
  float acc = 0.f;
  const float* p = partial + (size_t)g*POOL_S*2*C_HID;
  for (int j = 0; j < POOL_S*2; ++j)
    acc += p[j*C_HID + t];
  sums[t] = acc;
  __syncthreads();
  if (t < COUT){
    int rs = clampi(lower_bound_i(batch, N, g), 0, N);
    int re = clampi(lower_bound_i(batch, N, g + 1), rs, N);
    float inv = 1.0f / fmaxf((float)(re - rs), 1.0f);
    float o = 0.f;
    for (int k = 0; k < 128; ++k)
      o += sums[k] * Wl[k*COUT + t];
    out[g*COUT + t] = o * inv + bl[t];
  }
}

extern "C" void kernel_launch(void* const* d_in, const int* in_sizes, int n_in,
                              void* d_out, int out_size, void* d_ws, size_t ws_size,
                              hipStream_t stream){
  const float* x0 = (const float*)d_in[0];
  const int* ei   = (const int*)d_in[1];
  const int* batch= (const int*)d_in[2];
  const float* W1 = (const float*)d_in[3];
  const float* b1 = (const float*)d_in[4];
  const float* W2 = (const float*)d_in[5];
  const float* b2 = (const float*)d_in[6];
  const float* W3 = (const float*)d_in[7];
  const float* b3 = (const float*)d_in[8];
  const float* Wl = (const float*)d_in[9];
  const float* bl = (const float*)d_in[10];
  float* out = (float*)d_out;

  int E = in_sizes[1] / 2;
  int N = in_sizes[2];
  const int* src = ei;
  const int* dst = ei + E;
  int NBUK = (N + BKT - 1) / BKT;
  int chunk = (E + NBLK - 1) / NBLK;
  int ncnt = NBUK * NBLK;
  int nsb  = (ncnt + SCAN_CH - 1) / SCAN_CH;   // scan blocks

  size_t off_acc = 0;
  auto carve = [&](size_t bytes)->size_t{
    size_t r = off_acc; off_acc += (bytes + 255) & ~(size_t)255; return r;
  };
  size_t o_cnt   = carve((size_t)ncnt*4);
  size_t o_bases = carve((size_t)(ncnt+1)*4);
  size_t o_bsum  = carve(256*4);
  size_t o_bbase = carve(256*4);
  size_t o_offs  = carve((size_t)(N+1)*4);
  size_t o_dinv  = carve((size_t)N*4);
  size_t o_meta  = carve((size_t)E*4);                      // compact CSR src list
  size_t o_rec   = carve((size_t)E*4);                      // bucket-sorted records
  size_t o_yA    = carve((size_t)(N+1)*C_HID);              // fp8 ping (+ zero row N)
  size_t o_yB    = carve((size_t)(N+1)*C_HID);              // fp8 pong (+ zero row N)
  size_t o_aggb  = carve((size_t)N*C_HID*2);                // bf16 agg
  size_t o_wt    = carve((size_t)3*128*128*2);              // bf16 Wt x3
  size_t need = off_acc;

  // hbuf (bf16 h3, 25.6MB) aliases meta+rec+yA (all dead after spmm3)
  size_t hbuf_avail = o_aggb - o_meta;
  bool alias_ok = hbuf_avail >= (size_t)N*C_HID*2;
  // part (4MB) aliases yB (dead after spmm3); yB region is 12.8MB
  alias_ok = alias_ok &&
             ((size_t)(N+1)*C_HID >= (size_t)NGRAPH*POOL_S*2*C_HID*4);

  if (ws_size < need || NBUK > NBUK_MAX || nsb > 256 || !alias_ok){
    k_zero<<<(out_size+255)/256, 256, 0, stream>>>(out, out_size);
    return;
  }

  char* base = (char*)d_ws;
  int* cntg  = (int*)(base + o_cnt);
  int* bases = (int*)(base + o_bases);
  int* bsum  = (int*)(base + o_bsum);
  int* bbase = (int*)(base + o_bbase);
  int* offs  = (int*)(base + o_offs);
  float* dinv= (float*)(base + o_dinv);
  int* meta  = (int*)(base + o_meta);
  unsigned int* rec   = (unsigned int*)(base + o_rec);
  unsigned short* yA  = (unsigned short*)(base + o_yA);     // fp8 pairs as ushort
  unsigned short* yB  = (unsigned short*)(base + o_yB);
  unsigned int* aggb  = (unsigned int*)(base + o_aggb);
  unsigned short* wt  = (unsigned short*)(base + o_wt);
  unsigned short* hbuf= (unsigned short*)(base + o_meta);   // alias: meta+rec+yA region
  float* part         = (float*)(base + o_yB);              // alias: yB region

  k_cnt  <<<NBLK, 256, 0, stream>>>(dst, cntg, E, N, NBUK, chunk);
  k_scanA<<<nsb, 256, 0, stream>>>(cntg, bsum, ncnt);
  k_scanB<<<1, 256, 0, stream>>>(bsum, bbase, bases, nsb, ncnt);
  k_scanC<<<nsb, 256, 0, stream>>>(cntg, bbase, bases, ncnt);
  k_scat <<<NBLK, 256, 0, stream>>>(src, dst, bases, rec, E, N, NBUK, chunk);
  k_csr  <<<NBUK, BKT, 0, stream>>>(rec, bases, offs, dinv, meta, E, N, NBUK);

  k_xcast<<<(N*64 + 64 + 255)/256, 256, 0, stream>>>((const float2*)x0, dinv, yA, yB, N);
  k_prep <<<192, 256, 0, stream>>>(W1, W2, W3, wt);

  int spmm_grid = (N + 3) / 4;     // 4 waves/block, one wave per node

  k_spmm<<<spmm_grid, 256, 0, stream>>>(yA, offs, dinv, meta, aggb, N);
  k_gemm<true ><<<GEMM_BLOCKS, 256, 0, stream>>>((const unsigned short*)aggb, wt,           b1, dinv, (void*)yB, N);
  k_spmm<<<spmm_grid, 256, 0, stream>>>(yB, offs, dinv, meta, aggb, N);
  k_gemm<true ><<<GEMM_BLOCKS, 256, 0, stream>>>((const unsigned short*)aggb, wt + 16384,   b2, dinv, (void*)yA, N);
  k_spmm<<<spmm_grid, 256, 0, stream>>>(yA, offs, dinv, meta, aggb, N);
  k_gemm<false><<<GEMM_BLOCKS, 256, 0, stream>>>((const unsigned short*)aggb, wt + 2*16384, b3, dinv, (void*)hbuf, N);

  k_pool <<<NGRAPH*POOL_S, 128, 0, stream>>>((const unsigned int*)hbuf, batch, part, N);
  k_final<<<NGRAPH, 128, 0, stream>>>(part, batch, Wl, bl, out, N);
}

// Round 4
// 337.973 us; speedup vs baseline: 1.1475x; 1.1218x over previous
//
#include <hip/hip_runtime.h>
#include <stdint.h>

#define C_HID 128
#define NGRAPH 64
#define COUT 64
#define POOL_S 64     // pool chunks per graph
#define NBLK 256      // edge-chunk blocks for cnt/scat
#define BKT 256       // nodes per bucket
#define NBUK_MAX 512
#define SCAN_CH 4096  // scan elements per block (256 thr x 16)

typedef short bf16x8 __attribute__((ext_vector_type(8)));
typedef float f32x4 __attribute__((ext_vector_type(4)));
typedef float f32x2 __attribute__((ext_vector_type(2)));

__device__ __forceinline__ unsigned short f2bf(float f){
  unsigned int u = __builtin_bit_cast(unsigned int, f);
  u = u + 0x7FFFu + ((u >> 16) & 1u);   // RNE
  return (unsigned short)(u >> 16);
}
__device__ __forceinline__ float bflo(unsigned int u){
  return __builtin_bit_cast(float, u << 16);
}
__device__ __forceinline__ float bfhi(unsigned int u){
  return __builtin_bit_cast(float, u & 0xFFFF0000u);
}
__device__ __forceinline__ int clampi(int v, int lo, int hi){
  return v < lo ? lo : (v > hi ? hi : v);
}

__global__ void k_zero(float* __restrict__ out, int n){
  int i = blockIdx.x*blockDim.x + threadIdx.x;
  if (i < n) out[i] = 0.f;
}

// ---------- CSR build, pass 1: per-(block,bucket) histogram ----------
__global__ __launch_bounds__(256) void k_cnt(const int* __restrict__ dst,
                                             int* __restrict__ cntg,
                                             int E, int N, int NBUK, int chunk){
  __shared__ int cnt[NBUK_MAX];
  int blk = blockIdx.x, t = threadIdx.x;
  for (int b = t; b < NBUK; b += 256) cnt[b] = 0;
  __syncthreads();
  int e0 = blk*chunk, e1 = min(E, e0 + chunk);
  for (int e = e0 + t; e < e1; e += 256)
    atomicAdd(&cnt[clampi(dst[e], 0, N-1) >> 8], 1);
  __syncthreads();
  for (int b = t; b < NBUK; b += 256)
    cntg[b*NBLK + blk] = cnt[b];          // bucket-major layout for the scan
}

// ---------- pass 2: hierarchical exclusive scan of n counts ----------
__global__ __launch_bounds__(256) void k_scanA(const int* __restrict__ cnt,
                                               int* __restrict__ bsum, int n){
  __shared__ int red[256];
  int blk = blockIdx.x, t = threadIdx.x;
  int base = blk*SCAN_CH + t*16;
  int s = 0;
  #pragma unroll
  for (int j = 0; j < 16; ++j){ int i = base + j; s += (i < n) ? cnt[i] : 0; }
  red[t] = s; __syncthreads();
  for (int off = 128; off > 0; off >>= 1){
    if (t < off) red[t] += red[t + off];
    __syncthreads();
  }
  if (t == 0) bsum[blk] = red[0];
}

// single block; nb <= 256
__global__ __launch_bounds__(256) void k_scanB(const int* __restrict__ bsum,
                                               int* __restrict__ bbase,
                                               int* __restrict__ bases, int nb, int n){
  __shared__ int buf[256];
  int t = threadIdx.x;
  int v = (t < nb) ? bsum[t] : 0;
  buf[t] = v; __syncthreads();
  for (int off = 1; off < 256; off <<= 1){
    int add = (t >= off) ? buf[t-off] : 0;
    __syncthreads();
    buf[t] += add;
    __syncthreads();
  }
  if (t < nb) bbase[t] = buf[t] - v;       // exclusive
  if (t == nb-1) bases[n] = buf[t];        // total == E
}

__global__ __launch_bounds__(256) void k_scanC(const int* __restrict__ cnt,
                                               const int* __restrict__ bbase,
                                               int* __restrict__ bases, int n){
  __shared__ int buf[256];
  int blk = blockIdx.x, t = threadIdx.x;
  int base = blk*SCAN_CH + t*16;
  int loc[16]; int s = 0;
  #pragma unroll
  for (int j = 0; j < 16; ++j){ int i = base + j; loc[j] = (i < n) ? cnt[i] : 0; s += loc[j]; }
  buf[t] = s; __syncthreads();
  for (int off = 1; off < 256; off <<= 1){
    int add = (t >= off) ? buf[t-off] : 0;
    __syncthreads();
    buf[t] += add;
    __syncthreads();
  }
  int run = bbase[blk] + buf[t] - s;       // exclusive prefix for this thread
  #pragma unroll
  for (int j = 0; j < 16; ++j){
    int i = base + j;
    if (i < n) bases[i] = run;
    run += loc[j];
  }
}

// ---------- pass 3: scatter packed records into per-(block,bucket) segments ----------
__global__ __launch_bounds__(256) void k_scat(const int* __restrict__ src,
                                              const int* __restrict__ dst,
                                              const int* __restrict__ bases,
                                              unsigned int* __restrict__ rec,
                                              int E, int N, int NBUK, int chunk){
  __shared__ int cur[NBUK_MAX];
  int blk = blockIdx.x, t = threadIdx.x;
  for (int b = t; b < NBUK; b += 256) cur[b] = bases[b*NBLK + blk];
  __syncthreads();
  int e0 = blk*chunk, e1 = min(E, e0 + chunk);
  for (int e = e0 + t; e < e1; e += 256){
    int d = clampi(dst[e], 0, N-1);
    int s = clampi(src[e], 0, N-1);
    int p = atomicAdd(&cur[d >> 8], 1);    // LDS atomic
    rec[p] = (unsigned int)s | ((unsigned int)(d & 255) << 24);
  }
}

// ---------- pass 4: per-bucket local CSR (offs, dinv, meta) ----------
__global__ __launch_bounds__(256) void k_csr(const unsigned int* __restrict__ rec,
                                             const int* __restrict__ bases,
                                             int* __restrict__ offs, float* __restrict__ dinv,
                                             int* __restrict__ meta, int E, int N, int NBUK){
  __shared__ int cnt[BKT], loff[BKT], cur[BKT];
  int b = blockIdx.x, t = threadIdx.x;
  cnt[t] = 0;
  __syncthreads();
  int r0 = bases[b*NBLK];
  int r1 = (b+1 < NBUK) ? bases[(b+1)*NBLK] : E;
  for (int i = r0 + t; i < r1; i += 256)
    atomicAdd(&cnt[rec[i] >> 24], 1);
  __syncthreads();
  loff[t] = cnt[t];
  __syncthreads();
  for (int off = 1; off < BKT; off <<= 1){
    int add = (t >= off) ? loff[t - off] : 0;
    __syncthreads();
    loff[t] += add;
    __syncthreads();
  }
  int excl = loff[t] - cnt[t];
  cur[t] = r0 + excl;
  int node = b*BKT + t;
  if (node < N){
    offs[node] = r0 + excl;
    dinv[node] = rsqrtf((float)(cnt[t] + 1));   // +1 = self loop
  }
  if (b == NBUK-1 && t == 0) offs[N] = E;
  __syncthreads();
  for (int i = r0 + t; i < r1; i += 256){
    unsigned int r = rec[i];
    int p = atomicAdd(&cur[r >> 24], 1);
    meta[p] = (int)(r & 0x00FFFFFFu);
  }
}

// ---------- y0 = 64*dinv*x0, fp32 -> fp8 e4m3; zero row N of BOTH fp8 buffers ----------
// S=64 (exact pow2) keeps y values in e4m3's normal range (~0.1..80).
__global__ void k_xcast(const float2* __restrict__ x, const float* __restrict__ dinv,
                        unsigned short* __restrict__ y, unsigned short* __restrict__ y2, int N){
  int i = blockIdx.x*256 + threadIdx.x;
  int tot = N*64;
  if (i < tot){
    float2 v = x[i];
    float dn = dinv[i >> 6] * 64.f;
    int p = __builtin_amdgcn_cvt_pk_fp8_f32(v.x*dn, v.y*dn, 0, false);
    y[i] = (unsigned short)(p & 0xFFFF);
  } else if (i < tot + 64){
    y[i] = 0;                       // zero row at index N (gather sink)
    y2[i] = 0;
  }
}

// ---------- W fp32 [128][128] -> Wt bf16 [n][k] (3 weights) ----------
__global__ void k_prep(const float* __restrict__ W1, const float* __restrict__ W2,
                       const float* __restrict__ W3, unsigned short* __restrict__ Wt){
  int idx = blockIdx.x*256 + threadIdx.x;     // grid = 192 blocks
  int w = idx >> 14;                           // 16384 per weight
  int r = idx & 16383;
  int n = r & 127, k = r >> 7;
  const float* W = (w == 0) ? W1 : (w == 1) ? W2 : W3;
  Wt[(size_t)w*16384 + (size_t)n*128 + k] = f2bf(W[k*128 + n]);
}

// ---------- SpMM v4: agg[i] = (dinv[i]/64) * ( y[i] + sum_e y[src_e] ), y fp8 ----------
// 4 NODES per wave: lane = g*16 + c; group g owns node (node0+g), lane covers
// channel bytes c*8..c*8+7 (16 lanes x 8B = full 128B row). One dwordx2 gather
// per edge slot j serves all 4 nodes (512B/instr). meta entries 0..31 preloaded
// per-lane (mv0/mv1, N-padded); per-j broadcast via ds_swizzle immediate
// (BitMode src = (lane&0x10)|j — zero VALU setup, LDS pipe). No cross-lane
// reduce: accumulators stay lane-local; epilogue is one uint4 store per lane.
// v3 post-mortem: compiler register-minimized (VGPR=24) and re-serialized the
// "one round" plan; wave-per-node caps bytes-in-flight regardless of schedule.
__global__ __launch_bounds__(256) void k_spmm(const unsigned short* __restrict__ y,
                       const int* __restrict__ offs,
                       const float* __restrict__ dinv,
                       const int* __restrict__ meta,
                       unsigned int* __restrict__ agg, int N){
  int wv   = __builtin_amdgcn_readfirstlane(threadIdx.x >> 6);
  int lane = threadIdx.x & 63;
  int g = lane >> 4, c = lane & 15;
  int node0 = blockIdx.x*16 + wv*4;
  if (node0 >= N) return;

  // wave-uniform CSR bounds for the 4 nodes (s_loads)
  int eA = offs[node0];
  int eB = offs[min(node0+1, N)];
  int eC = offs[min(node0+2, N)];
  int eD = offs[min(node0+3, N)];
  int eE = offs[min(node0+4, N)];
  int c0 = eB-eA, c1 = eC-eB, c2 = eD-eC, c3 = eE-eD;
  int maxc = max(max(c0,c1), max(c2,c3));

  // per-lane group views
  int e0l  = (g==0) ? eA : (g==1) ? eB : (g==2) ? eC : eD;
  int cntl = (g==0) ? c0 : (g==1) ? c1 : (g==2) ? c2 : c3;
  int nodeg = node0 + g;
  bool nok = nodeg < N;
  int nself = nok ? nodeg : N;              // row N = zero row

  const uint2* yrow = (const uint2*)y;      // row = 16 x 8B

  // per-lane meta preload: entries 0..31 of this group's edge list, N-padded.
  // OOB reads land in the rec region (follows meta in workspace) — discarded.
  int mv0 = (c < cntl)      ? meta[e0l + c]      : N;
  int mv1 = (c + 16 < cntl) ? meta[e0l + c + 16] : N;
  uint2 us = yrow[(size_t)nself*16 + c];    // self row
  float dl = dinv[nok ? nodeg : 0];

  f32x2 acc[4];
  { f32x2 f;
    f = __builtin_amdgcn_cvt_pk_f32_fp8((int)us.x, false); acc[0] = f;
    f = __builtin_amdgcn_cvt_pk_f32_fp8((int)us.x, true);  acc[1] = f;
    f = __builtin_amdgcn_cvt_pk_f32_fp8((int)us.y, false); acc[2] = f;
    f = __builtin_amdgcn_cvt_pk_f32_fp8((int)us.y, true);  acc[3] = f; }

  uint2 u[8];
  // ds_swizzle BitMode: src_lane = ((lane&and)|or)^xor within 32-lane halves.
  // and=0x10 keeps the group bit, or=j&15 picks the entry lane.
#define SWZ0(J) __builtin_amdgcn_ds_swizzle(mv0, (0x10 | (((J)&15)<<5)))
#define SWZ1(J) __builtin_amdgcn_ds_swizzle(mv1, (0x10 | (((J)&15)<<5)))
#define GA(K, SM) u[K] = yrow[(size_t)(unsigned)(SM)*16 + c]
#define CONV8() do{ _Pragma("unroll") \
  for (int k2 = 0; k2 < 8; ++k2){ \
    f32x2 f; \
    f = __builtin_amdgcn_cvt_pk_f32_fp8((int)u[k2].x, false); acc[0] += f; \
    f = __builtin_amdgcn_cvt_pk_f32_fp8((int)u[k2].x, true);  acc[1] += f; \
    f = __builtin_amdgcn_cvt_pk_f32_fp8((int)u[k2].y, false); acc[2] += f; \
    f = __builtin_amdgcn_cvt_pk_f32_fp8((int)u[k2].y, true);  acc[3] += f; } }while(0)

  if (0 < maxc){                            // wave-uniform guards per batch of 8
    GA(0,SWZ0(0)); GA(1,SWZ0(1)); GA(2,SWZ0(2)); GA(3,SWZ0(3));
    GA(4,SWZ0(4)); GA(5,SWZ0(5)); GA(6,SWZ0(6)); GA(7,SWZ0(7));
    __builtin_amdgcn_sched_barrier(0);
    CONV8();
  }
  if (8 < maxc){
    GA(0,SWZ0(8)); GA(1,SWZ0(9)); GA(2,SWZ0(10)); GA(3,SWZ0(11));
    GA(4,SWZ0(12)); GA(5,SWZ0(13)); GA(6,SWZ0(14)); GA(7,SWZ0(15));
    __builtin_amdgcn_sched_barrier(0);
    CONV8();
  }
  if (16 < maxc){
    GA(0,SWZ1(16)); GA(1,SWZ1(17)); GA(2,SWZ1(18)); GA(3,SWZ1(19));
    GA(4,SWZ1(20)); GA(5,SWZ1(21)); GA(6,SWZ1(22)); GA(7,SWZ1(23));
    __builtin_amdgcn_sched_barrier(0);
    CONV8();
  }
  if (24 < maxc){
    GA(0,SWZ1(24)); GA(1,SWZ1(25)); GA(2,SWZ1(26)); GA(3,SWZ1(27));
    GA(4,SWZ1(28)); GA(5,SWZ1(29)); GA(6,SWZ1(30)); GA(7,SWZ1(31));
    __builtin_amdgcn_sched_barrier(0);
    CONV8();
  }
#undef SWZ0
#undef SWZ1
#undef GA
#undef CONV8

  // rare tail (deg > 32): per-lane meta load per slot
  for (int j = 32; j < maxc; ++j){
    int sm = (j < cntl) ? meta[e0l + j] : N;
    uint2 t = yrow[(size_t)(unsigned)sm*16 + c];
    f32x2 f;
    f = __builtin_amdgcn_cvt_pk_f32_fp8((int)t.x, false); acc[0] += f;
    f = __builtin_amdgcn_cvt_pk_f32_fp8((int)t.x, true);  acc[1] += f;
    f = __builtin_amdgcn_cvt_pk_f32_fp8((int)t.y, false); acc[2] += f;
    f = __builtin_amdgcn_cvt_pk_f32_fp8((int)t.y, true);  acc[3] += f;
  }

  float dn = dl * 0.015625f;   // /64
  if (nok){
    uint4 w;
    w.x = (unsigned int)f2bf(acc[0].x*dn) | ((unsigned int)f2bf(acc[0].y*dn) << 16);
    w.y = (unsigned int)f2bf(acc[1].x*dn) | ((unsigned int)f2bf(acc[1].y*dn) << 16);
    w.z = (unsigned int)f2bf(acc[2].x*dn) | ((unsigned int)f2bf(acc[2].y*dn) << 16);
    w.w = (unsigned int)f2bf(acc[3].x*dn) | ((unsigned int)f2bf(acc[3].y*dn) << 16);
    *(uint4*)(agg + (size_t)nodeg*64 + c*4) = w;   // 16 lanes x 16B = 256B row
  }
}

// ---------- GEMM: h = relu(A[Mx128] @ W + b); FP8OUT: y' = fp8(64*dinv*h), else bf16 h ----
#define GEMM_BLOCKS 512
template<bool FP8OUT>
__global__ __launch_bounds__(256) void k_gemm(const unsigned short* __restrict__ A,
                                              const unsigned short* __restrict__ Wt,
                                              const float* __restrict__ bias,
                                              const float* __restrict__ scale,
                                              void* __restrict__ outv, int M){
  __shared__ unsigned short wt[128*136];
  {
    const uint4* wsrc = (const uint4*)Wt;     // 4096 uint4 (8 shorts each)
    for (int i = threadIdx.x; i < 4096; i += 256){
      uint4 v = wsrc[i];
      int n = i >> 4, kblk = i & 15;          // row = 16 uint4
      *(uint4*)&wt[n*136 + kblk*8] = v;
    }
  }
  __syncthreads();

  int wv = threadIdx.x >> 6, lane = threadIdx.x & 63;
  int q = lane >> 4, ln = lane & 15;
  int tiles = (M + 63) >> 6;

  for (int tile = blockIdx.x; tile < tiles; tile += GEMM_BLOCKS){
    int m0 = tile*64 + wv*16;
    int arow = m0 + ln;
    bool arow_ok = (arow < M);
    int arow_s = arow_ok ? arow : 0;

    f32x4 zero = {0.f, 0.f, 0.f, 0.f};
    f32x4 acc[8];
    #pragma unroll
    for (int t = 0; t < 8; ++t) acc[t] = zero;

    #pragma unroll
    for (int kk = 0; kk < 4; ++kk){
      bf16x8 a;
      if (arow_ok){
        __builtin_memcpy(&a, A + (size_t)arow_s*128 + kk*32 + q*8, 16);
      } else {
        a = (bf16x8){0,0,0,0,0,0,0,0};
      }
      #pragma unroll
      for (int t = 0; t < 8; ++t){
        bf16x8 b;
        __builtin_memcpy(&b, &wt[(t*16 + ln)*136 + kk*32 + q*8], 16);
        acc[t] = __builtin_amdgcn_mfma_f32_16x16x32_bf16(a, b, acc[t], 0, 0, 0);
      }
    }
    float sc[4];
    #pragma unroll
    for (int r = 0; r < 4; ++r){
      int row = m0 + q*4 + r;
      sc[r] = (FP8OUT && row < M) ? scale[row] * 64.f : 1.0f;
    }
    #pragma unroll
    for (int t = 0; t < 8; ++t){
      float bv = bias[t*16 + ln];
      #pragma unroll
      for (int r = 0; r < 4; ++r){
        int row = m0 + q*4 + r;
        if (row < M){
          float v = acc[t][r] + bv;
          v = v > 0.f ? v : 0.f;
          if (FP8OUT){
            v *= sc[r];
            int p = __builtin_amdgcn_cvt_pk_fp8_f32(v, v, 0, false);
            ((unsigned char*)outv)[(size_t)row*128 + t*16 + ln] = (unsigned char)(p & 0xFF);
          } else {
            ((unsigned short*)outv)[(size_t)row*128 + t*16 + ln] = f2bf(v);
          }
        }
      }
    }
  }
}

// ---------- pooling ----------
__device__ __forceinline__ int lower_bound_i(const int* arr, int n, int val){
  int lo = 0, hi = n;
  while (lo < hi){ int mid = (lo + hi) >> 1; if (arr[mid] < val) lo = mid + 1; else hi = mid; }
  return lo;
}

__global__ void k_pool(const unsigned int* __restrict__ x, const int* __restrict__ batch,
                       float* __restrict__ partial, int N){
  int g = blockIdx.x / POOL_S, s = blockIdx.x % POOL_S;
  int h = threadIdx.x >> 6;
  int lane = threadIdx.x & 63;
  int rs = clampi(lower_bound_i(batch, N, g), 0, N);
  int re = clampi(lower_bound_i(batch, N, g + 1), rs, N);
  int len = re - rs;
  int a = rs + (int)(((long long)len * s) / POOL_S);
  int b = rs + (int)(((long long)len * (s + 1)) / POOL_S);
  float ax = 0.f, ay = 0.f;
  for (int i = a + h; i < b; i += 2){
    unsigned int u = x[(size_t)i*64 + lane];
    ax += bflo(u);
    ay += bfhi(u);
  }
  float* p = partial + ((size_t)(g*POOL_S + s)*2 + h)*C_HID;
  p[2*lane]   = ax;
  p[2*lane+1] = ay;
}

__global__ void k_final(const float* __restrict__ partial, const int* __restrict__ batch,
                        const float* __restrict__ Wl, const float* __restrict__ bl,
                        float* __restrict__ out, int N){
  __shared__ float sums[C_HID];
  int g = blockIdx.x;
  int t = threadIdx.x;
  float acc = 0.f;
  const float* p = partial + (size_t)g*POOL_S*2*C_HID;
  for (int j = 0; j < POOL_S*2; ++j)
    acc += p[j*C_HID + t];
  sums[t] = acc;
  __syncthreads();
  if (t < COUT){
    int rs = clampi(lower_bound_i(batch, N, g), 0, N);
    int re = clampi(lower_bound_i(batch, N, g + 1), rs, N);
    float inv = 1.0f / fmaxf((float)(re - rs), 1.0f);
    float o = 0.f;
    for (int k = 0; k < 128; ++k)
      o += sums[k] * Wl[k*COUT + t];
    out[g*COUT + t] = o * inv + bl[t];
  }
}

extern "C" void kernel_launch(void* const* d_in, const int* in_sizes, int n_in,
                              void* d_out, int out_size, void* d_ws, size_t ws_size,
                              hipStream_t stream){
  const float* x0 = (const float*)d_in[0];
  const int* ei   = (const int*)d_in[1];
  const int* batch= (const int*)d_in[2];
  const float* W1 = (const float*)d_in[3];
  const float* b1 = (const float*)d_in[4];
  const float* W2 = (const float*)d_in[5];
  const float* b2 = (const float*)d_in[6];
  const float* W3 = (const float*)d_in[7];
  const float* b3 = (const float*)d_in[8];
  const float* Wl = (const float*)d_in[9];
  const float* bl = (const float*)d_in[10];
  float* out = (float*)d_out;

  int E = in_sizes[1] / 2;
  int N = in_sizes[2];
  const int* src = ei;
  const int* dst = ei + E;
  int NBUK = (N + BKT - 1) / BKT;
  int chunk = (E + NBLK - 1) / NBLK;
  int ncnt = NBUK * NBLK;
  int nsb  = (ncnt + SCAN_CH - 1) / SCAN_CH;   // scan blocks

  size_t off_acc = 0;
  auto carve = [&](size_t bytes)->size_t{
    size_t r = off_acc; off_acc += (bytes + 255) & ~(size_t)255; return r;
  };
  size_t o_cnt   = carve((size_t)ncnt*4);
  size_t o_bases = carve((size_t)(ncnt+1)*4);
  size_t o_bsum  = carve(256*4);
  size_t o_bbase = carve(256*4);
  size_t o_offs  = carve((size_t)(N+1)*4);
  size_t o_dinv  = carve((size_t)N*4);
  size_t o_meta  = carve((size_t)E*4);                      // compact CSR src list
  size_t o_rec   = carve((size_t)E*4);                      // bucket-sorted records
  size_t o_yA    = carve((size_t)(N+1)*C_HID);              // fp8 ping (+ zero row N)
  size_t o_yB    = carve((size_t)(N+1)*C_HID);              // fp8 pong (+ zero row N)
  size_t o_aggb  = carve((size_t)N*C_HID*2);                // bf16 agg
  size_t o_wt    = carve((size_t)3*128*128*2);              // bf16 Wt x3
  size_t need = off_acc;

  // hbuf (bf16 h3, 25.6MB) aliases meta+rec+yA (all dead after spmm3)
  size_t hbuf_avail = o_aggb - o_meta;
  bool alias_ok = hbuf_avail >= (size_t)N*C_HID*2;
  // part (4MB) aliases yB (dead after spmm3); yB region is 12.8MB
  alias_ok = alias_ok &&
             ((size_t)(N+1)*C_HID >= (size_t)NGRAPH*POOL_S*2*C_HID*4);

  if (ws_size < need || NBUK > NBUK_MAX || nsb > 256 || !alias_ok){
    k_zero<<<(out_size+255)/256, 256, 0, stream>>>(out, out_size);
    return;
  }

  char* base = (char*)d_ws;
  int* cntg  = (int*)(base + o_cnt);
  int* bases = (int*)(base + o_bases);
  int* bsum  = (int*)(base + o_bsum);
  int* bbase = (int*)(base + o_bbase);
  int* offs  = (int*)(base + o_offs);
  float* dinv= (float*)(base + o_dinv);
  int* meta  = (int*)(base + o_meta);
  unsigned int* rec   = (unsigned int*)(base + o_rec);
  unsigned short* yA  = (unsigned short*)(base + o_yA);     // fp8 pairs as ushort
  unsigned short* yB  = (unsigned short*)(base + o_yB);
  unsigned int* aggb  = (unsigned int*)(base + o_aggb);
  unsigned short* wt  = (unsigned short*)(base + o_wt);
  unsigned short* hbuf= (unsigned short*)(base + o_meta);   // alias: meta+rec+yA region
  float* part         = (float*)(base + o_yB);              // alias: yB region

  k_cnt  <<<NBLK, 256, 0, stream>>>(dst, cntg, E, N, NBUK, chunk);
  k_scanA<<<nsb, 256, 0, stream>>>(cntg, bsum, ncnt);
  k_scanB<<<1, 256, 0, stream>>>(bsum, bbase, bases, nsb, ncnt);
  k_scanC<<<nsb, 256, 0, stream>>>(cntg, bbase, bases, ncnt);
  k_scat <<<NBLK, 256, 0, stream>>>(src, dst, bases, rec, E, N, NBUK, chunk);
  k_csr  <<<NBUK, BKT, 0, stream>>>(rec, bases, offs, dinv, meta, E, N, NBUK);

  k_xcast<<<(N*64 + 64 + 255)/256, 256, 0, stream>>>((const float2*)x0, dinv, yA, yB, N);
  k_prep <<<192, 256, 0, stream>>>(W1, W2, W3, wt);

  int spmm_grid = (N + 15) / 16;   // 4 waves/block, 4 nodes per wave

  k_spmm<<<spmm_grid, 256, 0, stream>>>(yA, offs, dinv, meta, aggb, N);
  k_gemm<true ><<<GEMM_BLOCKS, 256, 0, stream>>>((const unsigned short*)aggb, wt,           b1, dinv, (void*)yB, N);
  k_spmm<<<spmm_grid, 256, 0, stream>>>(yB, offs, dinv, meta, aggb, N);
  k_gemm<true ><<<GEMM_BLOCKS, 256, 0, stream>>>((const unsigned short*)aggb, wt + 16384,   b2, dinv, (void*)yA, N);
  k_spmm<<<spmm_grid, 256, 0, stream>>>(yA, offs, dinv, meta, aggb, N);
  k_gemm<false><<<GEMM_BLOCKS, 256, 0, stream>>>((const unsigned short*)aggb, wt + 2*16384, b3, dinv, (void*)hbuf, N);

  k_pool <<<NGRAPH*POOL_S, 128, 0, stream>>>((const unsigned int*)hbuf, batch, part, N);
  k_final<<<NGRAPH, 128, 0, stream>>>(part, batch, Wl, bl, out, N);
}